// Round 4
// baseline (319.987 us; speedup 1.0000x reference)
//
#include <hip/hip_runtime.h>

// Problem constants (B=16, C=64, H=W=128, num_heads=4). All tensors fp32.
#define HW      16384            // H*W
#define CPH     16               // channels per head
#define NBH     64               // B * num_heads
#define NSLICE  16               // k-slices per bh (gram blocks per bh)
#define KSLICE  (HW / NSLICE)    // 1024 k columns per gram block
#define TKT     256              // k columns per LDS tile
#define LS      260              // LDS row stride in floats (16B-aligned, bank-spread)
#define KPT     4                // k per thread in apply kernel (one float4)
#define PSTRIDE 288              // per-(bh,slice) partial: 256 gram + 16 sx + 16 sy

// ws layout (floats): P[bh][slice][PSTRIDE], plain stores (no atomics, no memset).
//   [0..255]   partial G[c][d] for this k-slice
//   [256..271] partial sum x^2 per row c
//   [272..287] partial sum y^2 per row d

// Raw barrier that does NOT drain vmcnt: LDS ordering is guaranteed by the
// explicit lgkmcnt(0); register-destined global loads stay in flight across
// the barrier (the compiler inserts counted vmcnt waits at the consuming LDS
// write). sched_barrier(0) pins ordering around the asm (guide rule #18).
__device__ __forceinline__ void barrier_lds_only() {
    asm volatile("s_waitcnt lgkmcnt(0)" ::: "memory");
    __builtin_amdgcn_sched_barrier(0);
    __builtin_amdgcn_s_barrier();
    __builtin_amdgcn_sched_barrier(0);
}

// Kernel 1: per (bh, slice): partial G[c][d] = sum_k x[c,k]*y[d,k]; sx; sy.
// Grid: NBH*NSLICE = 1024 blocks (4 blocks/CU via 34KB LDS), 256 threads.
// Reg-staged LDS pipeline: next tile's 8 float4 are issued right after this
// tile's LDS writes; with barrier_lds_only they remain in flight through the
// entire compute phase AND the next barrier (round-3 diagnosis: __syncthreads
// vmcnt(0)-drain capped in-flight bytes at ~5KB/CU -> 2 TB/s).
__global__ __launch_bounds__(256) void gram_kernel(
    const float* __restrict__ x,
    const float* __restrict__ y,
    float* __restrict__ ws)
{
    __shared__ float xs[16 * LS];
    __shared__ float ys[16 * LS];
    __shared__ float Gs[256];
    __shared__ float sxs[16], sys[16];

    const int blk  = blockIdx.x;
    const int bh   = blk >> 4;
    const int sl   = blk & 15;
    const int ks   = sl * KSLICE;
    const int t    = threadIdx.x;

    Gs[t] = 0.f;
    if (t < 16) { sxs[t] = 0.f; sys[t] = 0.f; }

    const int c0 = t & 3;          // strided c base
    const int d0 = (t >> 2) & 3;   // strided d base
    const int g  = t >> 4;         // k-group (16 cols per tile)

    const int srow = t >> 6;       // staging: row base 0..3 (this wave's row)
    const int scol = (t & 63) * 4; // staging: fixed col, 16B per lane

    float acc[4][4];
    #pragma unroll
    for (int i = 0; i < 4; ++i)
        #pragma unroll
        for (int j = 0; j < 4; ++j) acc[i][j] = 0.f;
    float sqx[4] = {0.f, 0.f, 0.f, 0.f};
    float sqy[4] = {0.f, 0.f, 0.f, 0.f};

    const float* xb = x + (size_t)bh * CPH * HW + ks;
    const float* yb = y + (size_t)bh * CPH * HW + ks;

    // prologue: stage tile 0 into registers
    float4 px[4], py[4];
    #pragma unroll
    for (int i = 0; i < 4; ++i) {
        const size_t off = (size_t)(i * 4 + srow) * HW + scol;
        px[i] = *reinterpret_cast<const float4*>(xb + off);
        py[i] = *reinterpret_cast<const float4*>(yb + off);
    }

    for (int kt = 0; kt < KSLICE; kt += TKT) {
        barrier_lds_only();   // prev tile fully consumed (covers Gs init too);
                              // px/py loads stay in flight across this barrier
        #pragma unroll
        for (int i = 0; i < 4; ++i) {
            *reinterpret_cast<float4*>(&xs[(i * 4 + srow) * LS + scol]) = px[i];
            *reinterpret_cast<float4*>(&ys[(i * 4 + srow) * LS + scol]) = py[i];
        }
        // issue next tile's loads now (px/py regs free again); they stay in
        // flight across B2 + the whole compute phase + next B1
        if (kt + TKT < KSLICE) {
            #pragma unroll
            for (int i = 0; i < 4; ++i) {
                const size_t off = (size_t)(i * 4 + srow) * HW + (kt + TKT) + scol;
                px[i] = *reinterpret_cast<const float4*>(xb + off);
                py[i] = *reinterpret_cast<const float4*>(yb + off);
            }
        }
        barrier_lds_only();   // tile visible to all waves

        // group g owns columns [g*16, g*16+16) of this tile
        #pragma unroll
        for (int kq = 0; kq < 16; kq += 4) {
            float4 xr[4], yr[4];
            #pragma unroll
            for (int i = 0; i < 4; ++i)
                xr[i] = *reinterpret_cast<const float4*>(&xs[(c0 + 4 * i) * LS + g * 16 + kq]);
            #pragma unroll
            for (int j = 0; j < 4; ++j)
                yr[j] = *reinterpret_cast<const float4*>(&ys[(d0 + 4 * j) * LS + g * 16 + kq]);
            #pragma unroll
            for (int i = 0; i < 4; ++i)
                #pragma unroll
                for (int j = 0; j < 4; ++j) {
                    acc[i][j] = fmaf(xr[i].x, yr[j].x, acc[i][j]);
                    acc[i][j] = fmaf(xr[i].y, yr[j].y, acc[i][j]);
                    acc[i][j] = fmaf(xr[i].z, yr[j].z, acc[i][j]);
                    acc[i][j] = fmaf(xr[i].w, yr[j].w, acc[i][j]);
                }
            if (d0 == 0) {
                #pragma unroll
                for (int i = 0; i < 4; ++i) {
                    sqx[i] = fmaf(xr[i].x, xr[i].x, sqx[i]);
                    sqx[i] = fmaf(xr[i].y, xr[i].y, sqx[i]);
                    sqx[i] = fmaf(xr[i].z, xr[i].z, sqx[i]);
                    sqx[i] = fmaf(xr[i].w, xr[i].w, sqx[i]);
                }
            }
            if (c0 == 0) {
                #pragma unroll
                for (int j = 0; j < 4; ++j) {
                    sqy[j] = fmaf(yr[j].x, yr[j].x, sqy[j]);
                    sqy[j] = fmaf(yr[j].y, yr[j].y, sqy[j]);
                    sqy[j] = fmaf(yr[j].z, yr[j].z, sqy[j]);
                    sqy[j] = fmaf(yr[j].w, yr[j].w, sqy[j]);
                }
            }
        }
    }

    // block-level reduction in LDS (cheap LDS atomics), then plain global store
    #pragma unroll
    for (int i = 0; i < 4; ++i)
        #pragma unroll
        for (int j = 0; j < 4; ++j)
            atomicAdd(&Gs[(c0 + 4 * i) * 16 + (d0 + 4 * j)], acc[i][j]);
    if (d0 == 0) {
        #pragma unroll
        for (int i = 0; i < 4; ++i) atomicAdd(&sxs[c0 + 4 * i], sqx[i]);
    }
    if (c0 == 0) {
        #pragma unroll
        for (int j = 0; j < 4; ++j) atomicAdd(&sys[d0 + 4 * j], sqy[j]);
    }
    __syncthreads();   // full barrier is fine here (once, end of kernel)

    float* P = ws + (size_t)(bh * NSLICE + sl) * PSTRIDE;
    P[t] = Gs[t];
    if (t < 16)       P[256 + t] = sxs[t];
    else if (t < 32)  P[272 + (t - 16)] = sys[t - 16];
}

// Kernel 2 (fused): reduce 16 gram partials -> normalize -> row softmax (attn1)
// + col softmax (attn2) in LDS, then apply:
//   out_x[d,k] = t2 * sum_c attn2[c][d]*x[c,k] + y[d,k]   (channels 0..63)
//   out_y[d,k] = t1 * sum_c attn1[c][d]*y[c,k] + x[d,k]   (channels 64..127)
// KPT=4 (float4 per thread), depth-2 row prefetch. No launch_bounds min-waves
// (round-2 lesson: forced VGPR caps -> scratch spill -> 3x write traffic).
__global__ __launch_bounds__(256) void apply_kernel(
    const float* __restrict__ x,
    const float* __restrict__ y,
    const float* __restrict__ ws,
    const float* __restrict__ t1p,
    const float* __restrict__ t2p,
    float* __restrict__ out)
{
    const int CHUNKS = HW / (256 * KPT);       // 16
    const int blk   = blockIdx.x;
    const int bh    = blk / CHUNKS;
    const int chunk = blk % CHUNKS;
    const int t     = threadIdx.x;
    const int k0    = chunk * (256 * KPT) + t * KPT;
    const int i     = t >> 4;
    const int j     = t & 15;

    __shared__ float  Es[256];
    __shared__ float2 Ws[256];
    __shared__ float  nxs[16], nys[16];

    // --- reduce the 16 per-slice partials (coalesced: contiguous in t per slice)
    const float* P = ws + (size_t)bh * NSLICE * PSTRIDE;
    float gsum = 0.f;
    #pragma unroll
    for (int s = 0; s < NSLICE; ++s) gsum += P[s * PSTRIDE + t];
    if (t < 32) {
        const int off = (t < 16) ? (256 + t) : (272 + (t - 16));
        float q = 0.f;
        #pragma unroll
        for (int s = 0; s < NSLICE; ++s) q += P[s * PSTRIDE + off];
        float n = fmaxf(sqrtf(q), 1e-12f);
        if (t < 16) nxs[t] = n; else nys[t - 16] = n;
    }
    __syncthreads();

    // --- normalized energy
    const float e = gsum / (nxs[i] * nys[j]);
    Es[t] = e;
    __syncthreads();

    // --- row softmax (attn1[i][j]) and col softmax (attn2[j][i])
    float rm = -1e30f;
    #pragma unroll
    for (int r = 0; r < 16; ++r) rm = fmaxf(rm, Es[i * 16 + r]);
    float rs = 0.f;
    #pragma unroll
    for (int r = 0; r < 16; ++r) rs += expf(Es[i * 16 + r] - rm);
    const float a1 = expf(e - rm) / rs;

    float cm = -1e30f;
    #pragma unroll
    for (int r = 0; r < 16; ++r) cm = fmaxf(cm, Es[r * 16 + j]);
    float cs = 0.f;
    #pragma unroll
    for (int r = 0; r < 16; ++r) cs += expf(Es[r * 16 + j] - cm);
    const float v2 = expf(e - cm) / cs;

    const float t1 = t1p[0];
    const float t2 = t2p[0];
    float* Wsf = reinterpret_cast<float*>(Ws);
    Wsf[(i * 16 + j) * 2 + 1] = t1 * a1;   // w1[c=i][d=j] = t1*attn1[i][j]
    Wsf[(j * 16 + i) * 2 + 0] = t2 * v2;   // w2[c=j][d=i] = t2*attn2[j][i]
    __syncthreads();

    // --- main apply loop (BW-bound; Ws reads are same-address broadcasts)
    const int b = bh >> 2;
    const int h = bh & 3;

    const float* xbase = x + ((size_t)bh * CPH) * HW + k0;
    const float* ybase = y + ((size_t)bh * CPH) * HW + k0;

    float accx[16][KPT];
    float accy[16][KPT];
    #pragma unroll
    for (int d = 0; d < 16; ++d)
        #pragma unroll
        for (int q = 0; q < KPT; ++q) { accx[d][q] = 0.f; accy[d][q] = 0.f; }

    // depth-2 rotating prefetch; loop fully unrolled so all indices are static
    float4 xq[2], yq[2];
    xq[0] = *reinterpret_cast<const float4*>(xbase);
    yq[0] = *reinterpret_cast<const float4*>(ybase);
    xq[1] = *reinterpret_cast<const float4*>(xbase + (size_t)1 * HW);
    yq[1] = *reinterpret_cast<const float4*>(ybase + (size_t)1 * HW);

    #pragma unroll
    for (int c = 0; c < 16; ++c) {
        const float4 xv = xq[c & 1];
        const float4 yv = yq[c & 1];
        if (c + 2 < 16) {   // issue loads for row c+2 before this row's FMAs
            xq[c & 1] = *reinterpret_cast<const float4*>(xbase + (size_t)(c + 2) * HW);
            yq[c & 1] = *reinterpret_cast<const float4*>(ybase + (size_t)(c + 2) * HW);
        }
        #pragma unroll
        for (int d = 0; d < 16; ++d) {
            float2 w = Ws[c * 16 + d];
            accx[d][0] = fmaf(w.x, xv.x, accx[d][0]);
            accx[d][1] = fmaf(w.x, xv.y, accx[d][1]);
            accx[d][2] = fmaf(w.x, xv.z, accx[d][2]);
            accx[d][3] = fmaf(w.x, xv.w, accx[d][3]);
            accy[d][0] = fmaf(w.y, yv.x, accy[d][0]);
            accy[d][1] = fmaf(w.y, yv.y, accy[d][1]);
            accy[d][2] = fmaf(w.y, yv.z, accy[d][2]);
            accy[d][3] = fmaf(w.y, yv.w, accy[d][3]);
        }
        // residual fold at d == c:  x_ += y[d],  y_ += x[d]
        accx[c][0] += yv.x;  accx[c][1] += yv.y;  accx[c][2] += yv.z;  accx[c][3] += yv.w;
        accy[c][0] += xv.x;  accy[c][1] += xv.y;  accy[c][2] += xv.z;  accy[c][3] += xv.w;
    }

    const size_t obx = ((size_t)b * 128 + h * 16) * HW + k0;   // x_ -> channels 0..63
    const size_t oby = obx + (size_t)64 * HW;                  // y_ -> channels 64..127
    #pragma unroll
    for (int d = 0; d < 16; ++d) {
        float4 px = make_float4(accx[d][0], accx[d][1], accx[d][2], accx[d][3]);
        float4 py = make_float4(accy[d][0], accy[d][1], accy[d][2], accy[d][3]);
        *reinterpret_cast<float4*>(out + obx + (size_t)d * HW) = px;
        *reinterpret_cast<float4*>(out + oby + (size_t)d * HW) = py;
    }
}

extern "C" void kernel_launch(void* const* d_in, const int* in_sizes, int n_in,
                              void* d_out, int out_size, void* d_ws, size_t ws_size,
                              hipStream_t stream) {
    const float* x  = (const float*)d_in[0];
    const float* y  = (const float*)d_in[1];
    const float* t1 = (const float*)d_in[2];
    const float* t2 = (const float*)d_in[3];
    float* ws  = (float*)d_ws;
    float* out = (float*)d_out;

    gram_kernel<<<NBH * NSLICE, 256, 0, stream>>>(x, y, ws);
    apply_kernel<<<NBH * (HW / (256 * KPT)), 256, 0, stream>>>(x, y, ws, t1, t2, out);
}

// Round 7
// 275.486 us; speedup vs baseline: 1.1615x; 1.1615x over previous
//
#include <hip/hip_runtime.h>

// Problem constants (B=16, C=64, H=W=128, num_heads=4). All tensors fp32.
#define HW      16384            // H*W
#define CPH     16               // channels per head
#define NBH     64               // B * num_heads
#define NSLICE  8                // k-blocks per bh (gram blocks per bh)
#define KBLK    (HW / NSLICE)    // 2048 k columns per gram block
#define KPT     4                // k per thread in apply kernel (one float4)
#define PSTRIDE 288              // per-(bh,slice) partial: 256 gram + 16 sx + 16 sy

// ws layout (floats): P[bh][slice][PSTRIDE], plain stores (no atomics, no memset).
//   [0..255]   partial G[c][d] for this k-slice
//   [256..271] partial sum x^2 per row c
//   [272..287] partial sum y^2 per row d

// Kernel 1 — wave-autonomous gram (no barriers, no LDS). Rounds 3/4 showed the
// LDS+barrier gram is latency-bound at 2 TB/s (compiler vmcnt(0)-drain at each
// barrier clips in-flight bytes). Here each wave owns one 8x8 (c,d) quadrant
// of G in 64 VGPRs, issues 16 independent float4 loads per 256-col k-stripe
// (16 KB in flight per wave, continuously), FMAs the outer product, then does
// a distributed-ownership shuffle reduction: lane l ends owning G-quadrant
// entry (i=l>>3, j=l&7) -> one parallel store. Duplicate row reads across the
// block's 4 waves are L1 hits; HBM traffic stays ~134 MB.
// Grid: NBH*NSLICE = 512 blocks, 256 threads (4 waves).
//   wave w: quadrant cq=(w>>1)*8, dq=(w&1)*8
//   norms: w0 -> sx[0..7], w3 -> sx[8..15], w2 -> sy[0..7], w1 -> sy[8..15]
__global__ __launch_bounds__(256) void gram_kernel(
    const float* __restrict__ x,
    const float* __restrict__ y,
    float* __restrict__ ws)
{
    const int blk  = blockIdx.x;
    const int bh   = blk >> 3;
    const int kb   = blk & 7;
    const int t    = threadIdx.x;
    const int w    = t >> 6;        // wave 0..3
    const int lane = t & 63;
    const int cq   = (w >> 1) * 8;  // c quadrant base
    const int dq   = (w & 1) * 8;   // d quadrant base

    const float* xb = x + (size_t)bh * CPH * HW + (size_t)cq * HW
                        + (size_t)kb * KBLK + (size_t)lane * 4;
    const float* yb = y + (size_t)bh * CPH * HW + (size_t)dq * HW
                        + (size_t)kb * KBLK + (size_t)lane * 4;

    float acc[64];
    #pragma unroll
    for (int v = 0; v < 64; ++v) acc[v] = 0.f;
    float sq[8] = {0.f, 0.f, 0.f, 0.f, 0.f, 0.f, 0.f, 0.f};
    const bool sq_is_x = (w == 0) || (w == 3);   // wave-uniform

    for (int it = 0; it < KBLK; it += 256) {
        float4 xr[8], yr[8];
        // 16 independent dwordx4 loads, all issued before any use.
        // Lane-consecutive addresses -> fully coalesced.
        #pragma unroll
        for (int i = 0; i < 8; ++i) {
            xr[i] = *reinterpret_cast<const float4*>(xb + (size_t)i * HW + it);
            yr[i] = *reinterpret_cast<const float4*>(yb + (size_t)i * HW + it);
        }
        #pragma unroll
        for (int i = 0; i < 8; ++i)
            #pragma unroll
            for (int j = 0; j < 8; ++j) {
                float a = acc[i * 8 + j];
                a = fmaf(xr[i].x, yr[j].x, a);
                a = fmaf(xr[i].y, yr[j].y, a);
                a = fmaf(xr[i].z, yr[j].z, a);
                a = fmaf(xr[i].w, yr[j].w, a);
                acc[i * 8 + j] = a;
            }
        #pragma unroll
        for (int i = 0; i < 8; ++i) {
            const float4 v = sq_is_x ? xr[i] : yr[i];
            sq[i] = fmaf(v.x, v.x, sq[i]);
            sq[i] = fmaf(v.y, v.y, sq[i]);
            sq[i] = fmaf(v.z, v.z, sq[i]);
            sq[i] = fmaf(v.w, v.w, sq[i]);
        }
    }

    // Distributed-ownership reduction over the 64 lanes (per-wave, no barrier).
    // Invariant: entering step s, acc[idx] holds value v=(idx<<s)|(lane&((1<<s)-1)),
    // already summed over lanes matching in bits [s..5]. Each step halves the
    // held count; after 6 steps lane l holds v==l summed over all 64 lanes.
    #pragma unroll
    for (int s = 0; s < 6; ++s) {
        const int m    = 1 << s;
        const int K    = 64 >> s;
        const int keep = (lane >> s) & 1;
        #pragma unroll
        for (int idx = 0; idx < K; idx += 2) {
            const float a = acc[idx]     + __shfl_xor(acc[idx],     m, 64);
            const float b = acc[idx + 1] + __shfl_xor(acc[idx + 1], m, 64);
            acc[idx >> 1] = keep ? b : a;   // writes stay below read indices
        }
    }
    // sq: 3 ownership steps (8 values -> 1), then 3 plain butterflies.
    #pragma unroll
    for (int s = 0; s < 3; ++s) {
        const int m    = 1 << s;
        const int K    = 8 >> s;
        const int keep = (lane >> s) & 1;
        #pragma unroll
        for (int idx = 0; idx < K; idx += 2) {
            const float a = sq[idx]     + __shfl_xor(sq[idx],     m, 64);
            const float b = sq[idx + 1] + __shfl_xor(sq[idx + 1], m, 64);
            sq[idx >> 1] = keep ? b : a;
        }
    }
    sq[0] += __shfl_xor(sq[0],  8, 64);
    sq[0] += __shfl_xor(sq[0], 16, 64);
    sq[0] += __shfl_xor(sq[0], 32, 64);   // every lane: sq total for row (lane&7)

    // Parallel stores: lane l owns G[(cq+(l>>3))][(dq+(l&7))]; lanes 0..7 store norms.
    float* P = ws + (size_t)(bh * NSLICE + kb) * PSTRIDE;
    P[(cq + (lane >> 3)) * 16 + (dq + (lane & 7))] = acc[0];
    if (lane < 8) {
        if (sq_is_x) P[256 + cq + lane] = sq[0];
        else         P[272 + dq + lane] = sq[0];
    }
}

// Kernel 2 (fused): reduce 8 gram partials -> normalize -> row softmax (attn1)
// + col softmax (attn2) in LDS, then apply:
//   out_x[d,k] = t2 * sum_c attn2[c][d]*x[c,k] + y[d,k]   (channels 0..63)
//   out_y[d,k] = t1 * sum_c attn1[c][d]*y[c,k] + x[d,k]   (channels 64..127)
// KPT=4 (float4 per thread), depth-2 row prefetch. No launch_bounds min-waves
// (round-2 lesson: forced VGPR caps -> scratch spill -> 3x write traffic).
// Unchanged from rounds 3/4 (passed).
__global__ __launch_bounds__(256) void apply_kernel(
    const float* __restrict__ x,
    const float* __restrict__ y,
    const float* __restrict__ ws,
    const float* __restrict__ t1p,
    const float* __restrict__ t2p,
    float* __restrict__ out)
{
    const int CHUNKS = HW / (256 * KPT);       // 16
    const int blk   = blockIdx.x;
    const int bh    = blk / CHUNKS;
    const int chunk = blk % CHUNKS;
    const int t     = threadIdx.x;
    const int k0    = chunk * (256 * KPT) + t * KPT;
    const int i     = t >> 4;
    const int j     = t & 15;

    __shared__ float  Es[256];
    __shared__ float2 Ws[256];
    __shared__ float  nxs[16], nys[16];

    // --- reduce the 8 per-slice partials (coalesced: contiguous in t per slice)
    const float* P = ws + (size_t)bh * NSLICE * PSTRIDE;
    float gsum = 0.f;
    #pragma unroll
    for (int s = 0; s < NSLICE; ++s) gsum += P[s * PSTRIDE + t];
    if (t < 32) {
        const int off = (t < 16) ? (256 + t) : (272 + (t - 16));
        float q = 0.f;
        #pragma unroll
        for (int s = 0; s < NSLICE; ++s) q += P[s * PSTRIDE + off];
        float n = fmaxf(sqrtf(q), 1e-12f);
        if (t < 16) nxs[t] = n; else nys[t - 16] = n;
    }
    __syncthreads();

    // --- normalized energy
    const float e = gsum / (nxs[i] * nys[j]);
    Es[t] = e;
    __syncthreads();

    // --- row softmax (attn1[i][j]) and col softmax (attn2[j][i])
    float rm = -1e30f;
    #pragma unroll
    for (int r = 0; r < 16; ++r) rm = fmaxf(rm, Es[i * 16 + r]);
    float rs = 0.f;
    #pragma unroll
    for (int r = 0; r < 16; ++r) rs += expf(Es[i * 16 + r] - rm);
    const float a1 = expf(e - rm) / rs;

    float cm = -1e30f;
    #pragma unroll
    for (int r = 0; r < 16; ++r) cm = fmaxf(cm, Es[r * 16 + j]);
    float cs = 0.f;
    #pragma unroll
    for (int r = 0; r < 16; ++r) cs += expf(Es[r * 16 + j] - cm);
    const float v2 = expf(e - cm) / cs;

    const float t1 = t1p[0];
    const float t2 = t2p[0];
    float* Wsf = reinterpret_cast<float*>(Ws);
    Wsf[(i * 16 + j) * 2 + 1] = t1 * a1;   // w1[c=i][d=j] = t1*attn1[i][j]
    Wsf[(j * 16 + i) * 2 + 0] = t2 * v2;   // w2[c=j][d=i] = t2*attn2[j][i]
    __syncthreads();

    // --- main apply loop (BW-bound; Ws reads are same-address broadcasts)
    const int b = bh >> 2;
    const int h = bh & 3;

    const float* xbase = x + ((size_t)bh * CPH) * HW + k0;
    const float* ybase = y + ((size_t)bh * CPH) * HW + k0;

    float accx[16][KPT];
    float accy[16][KPT];
    #pragma unroll
    for (int d = 0; d < 16; ++d)
        #pragma unroll
        for (int q = 0; q < KPT; ++q) { accx[d][q] = 0.f; accy[d][q] = 0.f; }

    // depth-2 rotating prefetch; loop fully unrolled so all indices are static
    float4 xq[2], yq[2];
    xq[0] = *reinterpret_cast<const float4*>(xbase);
    yq[0] = *reinterpret_cast<const float4*>(ybase);
    xq[1] = *reinterpret_cast<const float4*>(xbase + (size_t)1 * HW);
    yq[1] = *reinterpret_cast<const float4*>(ybase + (size_t)1 * HW);

    #pragma unroll
    for (int c = 0; c < 16; ++c) {
        const float4 xv = xq[c & 1];
        const float4 yv = yq[c & 1];
        if (c + 2 < 16) {   // issue loads for row c+2 before this row's FMAs
            xq[c & 1] = *reinterpret_cast<const float4*>(xbase + (size_t)(c + 2) * HW);
            yq[c & 1] = *reinterpret_cast<const float4*>(ybase + (size_t)(c + 2) * HW);
        }
        #pragma unroll
        for (int d = 0; d < 16; ++d) {
            float2 w = Ws[c * 16 + d];
            accx[d][0] = fmaf(w.x, xv.x, accx[d][0]);
            accx[d][1] = fmaf(w.x, xv.y, accx[d][1]);
            accx[d][2] = fmaf(w.x, xv.z, accx[d][2]);
            accx[d][3] = fmaf(w.x, xv.w, accx[d][3]);
            accy[d][0] = fmaf(w.y, yv.x, accy[d][0]);
            accy[d][1] = fmaf(w.y, yv.y, accy[d][1]);
            accy[d][2] = fmaf(w.y, yv.z, accy[d][2]);
            accy[d][3] = fmaf(w.y, yv.w, accy[d][3]);
        }
        // residual fold at d == c:  x_ += y[d],  y_ += x[d]
        accx[c][0] += yv.x;  accx[c][1] += yv.y;  accx[c][2] += yv.z;  accx[c][3] += yv.w;
        accy[c][0] += xv.x;  accy[c][1] += xv.y;  accy[c][2] += xv.z;  accy[c][3] += xv.w;
    }

    const size_t obx = ((size_t)b * 128 + h * 16) * HW + k0;   // x_ -> channels 0..63
    const size_t oby = obx + (size_t)64 * HW;                  // y_ -> channels 64..127
    #pragma unroll
    for (int d = 0; d < 16; ++d) {
        float4 px = make_float4(accx[d][0], accx[d][1], accx[d][2], accx[d][3]);
        float4 py = make_float4(accy[d][0], accy[d][1], accy[d][2], accy[d][3]);
        *reinterpret_cast<float4*>(out + obx + (size_t)d * HW) = px;
        *reinterpret_cast<float4*>(out + oby + (size_t)d * HW) = py;
    }
}

extern "C" void kernel_launch(void* const* d_in, const int* in_sizes, int n_in,
                              void* d_out, int out_size, void* d_ws, size_t ws_size,
                              hipStream_t stream) {
    const float* x  = (const float*)d_in[0];
    const float* y  = (const float*)d_in[1];
    const float* t1 = (const float*)d_in[2];
    const float* t2 = (const float*)d_in[3];
    float* ws  = (float*)d_ws;
    float* out = (float*)d_out;

    gram_kernel<<<NBH * NSLICE, 256, 0, stream>>>(x, y, ws);
    apply_kernel<<<NBH * (HW / (256 * KPT)), 256, 0, stream>>>(x, y, ws, t1, t2, out);
}